// Round 5
// baseline (446.794 us; speedup 1.0000x reference)
//
#include <hip/hip_runtime.h>
#include <stdint.h>

typedef unsigned short u16;
typedef __attribute__((ext_vector_type(8))) short short8_t;   // 8 x bf16 (4 VGPRs)
typedef __attribute__((ext_vector_type(4))) float f32x4;

typedef const __attribute__((address_space(1))) void GV;
typedef __attribute__((address_space(3))) void LV;

__device__ __forceinline__ void gload_lds16(const void* g, void* l) {
  // async global->LDS, 16B per lane; LDS dest is wave-uniform base + lane*16
  __builtin_amdgcn_global_load_lds((GV*)g, (LV*)l, 16, 0, 0);
}

__device__ __forceinline__ u16 f2bf(float f) {
  union { float f; uint32_t u; } v; v.f = f;
  return (u16)((v.u + 0x7FFFu + ((v.u >> 16) & 1u)) >> 16);  // RNE
}

__device__ __forceinline__ f32x4 fz4() { f32x4 v = {0.f, 0.f, 0.f, 0.f}; return v; }

// ---------------- cast fp32 -> bf16 (4 elems/thread) ----------------
__global__ __launch_bounds__(256) void cast_kernel(const float* __restrict__ in,
                                                   u16* __restrict__ out) {
  int i = (blockIdx.x * 256 + threadIdx.x) * 4;
  float4 v = *(const float4*)(in + i);
  ushort4 o;
  o.x = f2bf(v.x); o.y = f2bf(v.y); o.z = f2bf(v.z); o.w = f2bf(v.w);
  *(ushort4*)(out + i) = o;
}

// ---------------- NT GEMM: C[M,N] = A[M,K] * B[N,K]^T + bias (m97 structure) --------
template <int OUT_BF16>
__global__ __launch_bounds__(256) void gemm_nt(const u16* __restrict__ A,
                                               const u16* __restrict__ B,
                                               const float* __restrict__ bias,
                                               void* __restrict__ Cout,
                                               int M, int N, int K) {
  __shared__ u16 As[128 * 32];  // [row][k], 64B rows
  __shared__ u16 Bs[128 * 32];
  const int tid = threadIdx.x, w = tid >> 6, l = tid & 63;
  const int m0 = blockIdx.y * 128, n0 = blockIdx.x * 128;
  const int wr = (w >> 1) * 64, wc = (w & 1) * 64;
  const int g = l >> 4;
  f32x4 acc[4][4];
#pragma unroll
  for (int i = 0; i < 4; ++i)
#pragma unroll
    for (int n = 0; n < 4; ++n) acc[i][n] = fz4();

  for (int kt = 0; kt < K; kt += 32) {
    __syncthreads();
#pragma unroll
    for (int i = 0; i < 2; ++i) {
      const int c = w * 2 + i;                 // chunk 0..7, 16 rows each
      const int row = c * 16 + (l >> 2);
      const int kcol = kt + (l & 3) * 8;
      gload_lds16(A + (size_t)(m0 + row) * K + kcol, (char*)As + c * 1024);
      gload_lds16(B + (size_t)(n0 + row) * K + kcol, (char*)Bs + c * 1024);
    }
    asm volatile("s_waitcnt vmcnt(0)");
    __syncthreads();
    short8_t af[4], bf[4];
#pragma unroll
    for (int i = 0; i < 4; ++i) {
      const int row = wr + i * 16 + (l & 15);
      af[i] = *(const short8_t*)((const char*)As + row * 64 + g * 16);
    }
#pragma unroll
    for (int n = 0; n < 4; ++n) {
      const int row = wc + n * 16 + (l & 15);
      bf[n] = *(const short8_t*)((const char*)Bs + row * 64 + g * 16);
    }
#pragma unroll
    for (int i = 0; i < 4; ++i)
#pragma unroll
      for (int n = 0; n < 4; ++n)
        acc[i][n] = __builtin_amdgcn_mfma_f32_16x16x32_bf16(af[i], bf[n], acc[i][n], 0, 0, 0);
  }

#pragma unroll
  for (int i = 0; i < 4; ++i) {
#pragma unroll
    for (int n = 0; n < 4; ++n) {
      const int col = n0 + wc + n * 16 + (l & 15);
      const float bv = bias[col];
      const int rowb = m0 + wr + i * 16 + g * 4;     // C/D: col=lane&15, row=(lane>>4)*4+j
#pragma unroll
      for (int j = 0; j < 4; ++j) {
        const float vv = acc[i][n][j] + bv;
        if (OUT_BF16)
          ((u16*)Cout)[(size_t)(rowb + j) * N + col] = f2bf(vv);
        else
          ((float*)Cout)[(size_t)(rowb + j) * N + col] = vv;
      }
    }
  }
}

// ---------------- V -> V^T per (h,b): VT[hb][d][t] ----------------
__global__ __launch_bounds__(256) void transpose_v(const u16* __restrict__ V,
                                                   u16* __restrict__ VT) {
  __shared__ u16 t[64][68];
  const int hb = blockIdx.z;
  const int t0 = blockIdx.x * 64, d0 = blockIdx.y * 64;
  const u16* src = V + (size_t)hb * 1024 * 256;
  u16* dst = VT + (size_t)hb * 256 * 1024;
  const int tid = threadIdx.x;
#pragma unroll
  for (int i = 0; i < 4; ++i) {
    const int idx = i * 256 + tid;
    const int r = idx >> 4, c4 = (idx & 15) * 4;   // r: t-row, c4: d-col
    ushort4 v = *(const ushort4*)(src + (size_t)(t0 + r) * 256 + d0 + c4);
    *(ushort4*)&t[r][c4] = v;
  }
  __syncthreads();
#pragma unroll
  for (int i = 0; i < 4; ++i) {
    const int idx = i * 256 + tid;
    const int r = idx >> 4, c4 = (idx & 15) * 4;   // r: d-row, c4: t-col
    ushort4 v;
    v.x = t[c4][r]; v.y = t[c4 + 1][r]; v.z = t[c4 + 2][r]; v.w = t[c4 + 3][r];
    *(ushort4*)(dst + (size_t)(d0 + r) * 1024 + t0 + c4) = v;
  }
}

// ---------------- fused attention (swapped-QK, dbuf KT=32, 2-phase pipeline) ----------
// Q,K: [hb][1024][256] bf16; VT: [hb][256][1024] bf16; adj: [b][1024][1024] f32
// 512 threads / 8 waves, 128 q-rows/block (16 per wave). S^T = mfma(K,Q): lane owns q.
// NOTE: launch_bounds min-waves=2 (NOT 4 — R2 showed 4 caps VGPR at 64 -> scratch spill).
// Block->work mapping: per-XCD order b(outer) -> qb -> h(fastest):
//   - each hb's K/VT (1MB) is swept by its 8 qb-blocks on ONE XCD => L2 reuse
//   - 4 heads sharing an adj row-slice stay temporally adjacent => adj L2 reuse
__global__ __launch_bounds__(512, 2) void attn_kernel(const u16* __restrict__ Q,
                                                      const u16* __restrict__ Kf,
                                                      const u16* __restrict__ VT,
                                                      const float* __restrict__ adj,
                                                      u16* __restrict__ O) {
  __shared__ u16 Ks[2][32 * 256];   // dbuf K tile [key][d], 512B rows, XOR slots
  __shared__ u16 Vs[2][256 * 32];   // dbuf V^T tile [d][key], 64B rows, XOR slots
  __shared__ u16 Ps[8][16 * 32];    // per-wave P^T staging, 64B rows, XOR slots
  const int tid = threadIdx.x, w = tid >> 6, l = tid & 63;
  const int g = l >> 4, q = l & 15;
  const int bid = blockIdx.x;
  const int xcd = bid & 7, idx = bid >> 3;           // 8 XCDs x 64 blocks
  const int b = xcd * 2 + (idx >> 5);                // 2 batches per XCD
  const int qb = (idx >> 2) & 7, h = idx & 3;        // qb sweeps, h fastest
  const int hb = h * 16 + b;
  const int q0 = qb * 128;
  const u16* qb_p = Q + ((size_t)hb * 1024 + q0 + w * 16) * 256;
  const u16* kb = Kf + (size_t)hb * 1024 * 256;
  const u16* vtb = VT + (size_t)hb * 256 * 1024;
  const float* adjr = adj + (size_t)b * 1024 * 1024 + (size_t)(q0 + w * 16 + q) * 1024;

  // Q fragments (B-operand of S^T): lane q=l&15, d = kk*32 + g*8 + j
  short8_t qf[8];
#pragma unroll
  for (int kk = 0; kk < 8; ++kk)
    qf[kk] = *(const short8_t*)(qb_p + (size_t)q * 256 + kk * 32 + g * 8);

  f32x4 o[16];  // O^T accum: lane holds O[q][d], d = n*16 + g*4 + r
#pragma unroll
  for (int n = 0; n < 16; ++n) o[n] = fz4();
  float mrun = -1e30f, lrun = 0.f;

#define STAGE_KV(ktt, bufi)                                                        \
  {                                                                                \
    _Pragma("unroll") for (int i_ = 0; i_ < 2; ++i_) {                             \
      const int c_ = w * 2 + i_;                                                   \
      const int row_ = 2 * c_ + (l >> 5);                                          \
      const int gcb_ = ((l & 31) ^ (row_ & 7)) * 16;                               \
      gload_lds16((const char*)(kb + (size_t)((ktt) * 32 + row_) * 256) + gcb_,    \
                  (char*)Ks[bufi] + c_ * 1024);                                    \
    }                                                                              \
    _Pragma("unroll") for (int i_ = 0; i_ < 2; ++i_) {                             \
      const int c_ = w * 2 + i_;                                                   \
      const int dr_ = c_ * 16 + (l >> 2);                                          \
      const int sl_ = (l & 3) ^ ((dr_ >> 1) & 3);                                  \
      gload_lds16((const char*)(vtb + (size_t)dr_ * 1024 + (ktt) * 32) + sl_ * 16, \
                  (char*)Vs[bufi] + c_ * 1024);                                    \
    }                                                                              \
  }

  // prologue: stage tile 0, prefetch adj tile 0
  STAGE_KV(0, 0);
  float4 a0 = *(const float4*)(adjr + 0 * 32 + 0 * 16 + g * 4);
  float4 a1 = *(const float4*)(adjr + 0 * 32 + 1 * 16 + g * 4);
  __syncthreads();

  for (int kt = 0; kt < 32; ++kt) {
    const int cur = kt & 1;
    float4 n0v = a0, n1v = a1;
    if (kt < 31) {
      STAGE_KV(kt + 1, cur ^ 1);
      n0v = *(const float4*)(adjr + (kt + 1) * 32 + 0 * 16 + g * 4);
      n1v = *(const float4*)(adjr + (kt + 1) * 32 + 1 * 16 + g * 4);
    }

    // S^T = K Q^T : 2 key-frags x 8 d-steps. lane: q=l&15, k = f*16 + g*4 + r
    f32x4 s[2];
    const char* kbuf = (const char*)Ks[cur];
    __builtin_amdgcn_s_setprio(1);
#pragma unroll
    for (int f = 0; f < 2; ++f) {
      f32x4 a = fz4();
      const int row = f * 16 + q;
      const char* kr = kbuf + row * 512;
#pragma unroll
      for (int kk = 0; kk < 8; ++kk) {
        const int cb = kk * 64 + g * 16;
        short8_t kfr = *(const short8_t*)(kr + (cb ^ ((row & 7) << 4)));
        a = __builtin_amdgcn_mfma_f32_16x16x32_bf16(kfr, qf[kk], a, 0, 0, 0);
      }
      s[f] = a;
    }
    __builtin_amdgcn_s_setprio(0);

    // scale + adj (vectorized float4 per frag)
#pragma unroll
    for (int j = 0; j < 4; ++j) {
      s[0][j] = s[0][j] * 0.03125f + ((const float*)&a0)[j];
      s[1][j] = s[1][j] * 0.03125f + ((const float*)&a1)[j];
    }

    // per-lane online softmax: 8 local values + reduce across g (xor 16,32)
    float pmax = s[0][0];
#pragma unroll
    for (int j = 1; j < 4; ++j) pmax = fmaxf(pmax, s[0][j]);
#pragma unroll
    for (int j = 0; j < 4; ++j) pmax = fmaxf(pmax, s[1][j]);
    pmax = fmaxf(pmax, __shfl_xor(pmax, 16));
    pmax = fmaxf(pmax, __shfl_xor(pmax, 32));

    if (!__all(pmax - mrun <= 8.0f)) {          // T13 defer-max
      const float mn = fmaxf(mrun, pmax);
      const float al = __expf(mrun - mn);
      mrun = mn;
      lrun *= al;
#pragma unroll
      for (int n = 0; n < 16; ++n)
#pragma unroll
        for (int r = 0; r < 4; ++r) o[n][r] *= al;
    }

    float sum = 0.f;
#pragma unroll
    for (int f = 0; f < 2; ++f)
#pragma unroll
      for (int j = 0; j < 4; ++j) {
        const float p = __expf(s[f][j] - mrun);
        s[f][j] = p;
        sum += p;
      }
    sum += __shfl_xor(sum, 16);
    sum += __shfl_xor(sum, 32);
    lrun += sum;

    // P^T -> LDS (per-wave [q][k] rows of 64B, XOR-swizzled 16B slots)
    {
      char* pw = (char*)Ps[w] + q * 64;
      const int swz = (q >> 1) & 3;
#pragma unroll
      for (int f = 0; f < 2; ++f) {
        ushort4 pk;
        pk.x = f2bf(s[f][0]); pk.y = f2bf(s[f][1]);
        pk.z = f2bf(s[f][2]); pk.w = f2bf(s[f][3]);
        *(ushort4*)(pw + ((f * 32 + g * 8) ^ (swz << 4))) = pk;
      }
    }
    asm volatile("s_waitcnt lgkmcnt(0)");
    __builtin_amdgcn_sched_barrier(0);
    short8_t pa = *(const short8_t*)((const char*)Ps[w] + q * 64 +
                                     ((g * 16) ^ (((q >> 1) & 3) << 4)));

    // O^T += V^T P^T : 16 d-frags, one k-step (K=32 keys)
    const char* vbuf = (const char*)Vs[cur];
    __builtin_amdgcn_s_setprio(1);
#pragma unroll
    for (int n = 0; n < 16; ++n) {
      const int dr = n * 16 + q;
      const int sl = g ^ ((dr >> 1) & 3);
      short8_t vf = *(const short8_t*)(vbuf + dr * 64 + sl * 16);
      o[n] = __builtin_amdgcn_mfma_f32_16x16x32_bf16(vf, pa, o[n], 0, 0, 0);
    }
    __builtin_amdgcn_s_setprio(0);

    __syncthreads();
    a0 = n0v; a1 = n1v;
  }
#undef STAGE_KV

  // epilogue: normalize, packed 8B stores; lane owns row q, d = n*16+g*4+r
  const float inv = 1.0f / lrun;
  u16* ob = O + ((size_t)hb * 1024 + q0 + w * 16 + q) * 256;
#pragma unroll
  for (int n = 0; n < 16; ++n) {
    ushort4 st;
    st.x = f2bf(o[n][0] * inv); st.y = f2bf(o[n][1] * inv);
    st.z = f2bf(o[n][2] * inv); st.w = f2bf(o[n][3] * inv);
    *(ushort4*)(ob + n * 16 + g * 4) = st;
  }
}

extern "C" void kernel_launch(void* const* d_in, const int* in_sizes, int n_in,
                              void* d_out, int out_size, void* d_ws, size_t ws_size,
                              hipStream_t stream) {
  (void)in_sizes; (void)n_in; (void)out_size; (void)ws_size;
  const float* x   = (const float*)d_in[0];
  const float* y   = (const float*)d_in[1];
  const float* adj = (const float*)d_in[2];
  const float* Wq  = (const float*)d_in[3];
  const float* bq  = (const float*)d_in[4];
  const float* Wk  = (const float*)d_in[5];
  const float* bk  = (const float*)d_in[6];
  const float* Wv  = (const float*)d_in[7];
  const float* bv  = (const float*)d_in[8];
  const float* Wo  = (const float*)d_in[9];
  const float* bo  = (const float*)d_in[10];

  char* ws = (char*)d_ws;
  const size_t MB = 1ull << 20;
  u16* Xb  = (u16*)(ws + 0);        // 32MB, reused as Tmp after Q GEMM
  u16* Yb  = (u16*)(ws + 32 * MB);  // 32MB
  u16* Wqb = (u16*)(ws + 64 * MB);  // 2MB each
  u16* Wkb = (u16*)(ws + 66 * MB);
  u16* Wvb = (u16*)(ws + 68 * MB);
  u16* Wob = (u16*)(ws + 70 * MB);
  u16* Qb  = (u16*)(ws + 72 * MB);  // 32MB
  u16* Kb  = (u16*)(ws + 104 * MB);
  u16* Vb  = (u16*)(ws + 136 * MB);
  u16* VTb = (u16*)(ws + 168 * MB); // peak 200MB
  u16* Tmp = Xb;

  cast_kernel<<<16384, 256, 0, stream>>>(x, Xb);
  cast_kernel<<<16384, 256, 0, stream>>>(y, Yb);
  cast_kernel<<<1024, 256, 0, stream>>>(Wq, Wqb);
  cast_kernel<<<1024, 256, 0, stream>>>(Wk, Wkb);
  cast_kernel<<<1024, 256, 0, stream>>>(Wv, Wvb);
  cast_kernel<<<1024, 256, 0, stream>>>(Wo, Wob);

  dim3 gg(8, 128);
  gemm_nt<1><<<gg, 256, 0, stream>>>(Xb, Wqb, bq, Qb, 16384, 1024, 1024);
  gemm_nt<1><<<gg, 256, 0, stream>>>(Yb, Wkb, bk, Kb, 16384, 1024, 1024);
  gemm_nt<1><<<gg, 256, 0, stream>>>(Yb, Wvb, bv, Vb, 16384, 1024, 1024);

  transpose_v<<<dim3(16, 4, 64), 256, 0, stream>>>(Vb, VTb);

  attn_kernel<<<512, 512, 0, stream>>>(Qb, Kb, VTb, adj, Tmp);

  gemm_nt<0><<<gg, 256, 0, stream>>>(Tmp, Wob, bo, d_out, 16384, 1024, 1024);
}

// Round 6
// 383.674 us; speedup vs baseline: 1.1645x; 1.1645x over previous
//
#include <hip/hip_runtime.h>
#include <stdint.h>

typedef unsigned short u16;
typedef __attribute__((ext_vector_type(8))) short short8_t;   // 8 x bf16 (4 VGPRs)
typedef __attribute__((ext_vector_type(4))) float f32x4;

typedef const __attribute__((address_space(1))) void GV;
typedef __attribute__((address_space(3))) void LV;

__device__ __forceinline__ void gload_lds16(const void* g, void* l) {
  // async global->LDS, 16B per lane; LDS dest is wave-uniform base + lane*16
  __builtin_amdgcn_global_load_lds((GV*)g, (LV*)l, 16, 0, 0);
}

__device__ __forceinline__ u16 f2bf(float f) {
  union { float f; uint32_t u; } v; v.f = f;
  return (u16)((v.u + 0x7FFFu + ((v.u >> 16) & 1u)) >> 16);  // RNE
}

__device__ __forceinline__ f32x4 fz4() { f32x4 v = {0.f, 0.f, 0.f, 0.f}; return v; }

// ---------------- cast fp32 -> bf16 (4 elems/thread) ----------------
__global__ __launch_bounds__(256) void cast_kernel(const float* __restrict__ in,
                                                   u16* __restrict__ out) {
  int i = (blockIdx.x * 256 + threadIdx.x) * 4;
  float4 v = *(const float4*)(in + i);
  ushort4 o;
  o.x = f2bf(v.x); o.y = f2bf(v.y); o.z = f2bf(v.z); o.w = f2bf(v.w);
  *(ushort4*)(out + i) = o;
}

// ======== 256x256 8-phase GEMM (T2+T3+T4+T5): C[M,N] = A[M,K]*B[N,K]^T + bias ========
// 512 threads / 8 waves (2M x 4N), per-wave 128x64 output, BK=64, 16 K-tiles (K=1024).
// LDS 128KB: A,B double-buffered 256x64 bf16 tiles, rows 128B, st_16x32 XOR swizzle
// (stored slot = logical slot ^ ((row>>2&1)<<1); inverse applied on global source).
// Schedule per tile S, 4 phases p:
//   p: dsread 4 A-frags (+8 B-frags at p0) | issue 1 half-tile stage:
//      p0/p1: A(S+1) h0/h1  (overwrites A(S-1), last read at S-1 p3 -> safe)
//      p2/p3: B(S+2) h0/h1  (overwrites B(S),   last read at S   p0 -> safe)
//   p3 only: counted vmcnt(4) (leaves B(S+2) in flight) -> fences tile S+1's reads
//   s_barrier; lgkmcnt(0); sched_barrier; setprio(1); 16 MFMA; setprio(0); s_barrier
template <int OUT_BF16>
__global__ __launch_bounds__(512, 2) void gemm8(const u16* __restrict__ A,
                                                const u16* __restrict__ B,
                                                const float* __restrict__ bias,
                                                void* __restrict__ Cout,
                                                int M, int N, int K) {
  __shared__ u16 Al[2 * 16384];   // [buf][half 128 rows][64 k] swizzled
  __shared__ u16 Bl[2 * 16384];
  const int tid = threadIdx.x, w = tid >> 6, l = tid & 63;
  const int g = l >> 4, q = l & 15;
  const int n0 = blockIdx.x * 256, m0 = blockIdx.y * 256;
  const int wr = (w >> 2) * 128, wc = (w & 3) * 64;
  const int NT = K >> 6;
  const int ah = w >> 2;            // this wave's A half
  const int bh = (w & 3) >> 1;      // this wave's B half
  const int brow0 = ((w & 3) & 1) * 64;

#define STAGE_A(S, half)                                                          \
  {                                                                               \
    _Pragma("unroll") for (int j_ = 0; j_ < 2; ++j_) {                            \
      const int idx_ = j_ * 512 + tid;                                            \
      const int row_ = idx_ >> 3;                                                 \
      const int sl_ = (idx_ & 7) ^ (((idx_ >> 5) & 1) << 1);                      \
      gload_lds16(A + (size_t)(m0 + (half) * 128 + row_) * K + (S) * 64 + sl_ * 8,\
                  Al + ((S) & 1) * 16384 + (half) * 8192 + (j_ * 512 + w * 64) * 8);\
    }                                                                             \
  }
#define STAGE_B(S, half)                                                          \
  {                                                                               \
    _Pragma("unroll") for (int j_ = 0; j_ < 2; ++j_) {                            \
      const int idx_ = j_ * 512 + tid;                                            \
      const int row_ = idx_ >> 3;                                                 \
      const int sl_ = (idx_ & 7) ^ (((idx_ >> 5) & 1) << 1);                      \
      gload_lds16(B + (size_t)(n0 + (half) * 128 + row_) * K + (S) * 64 + sl_ * 8,\
                  Bl + ((S) & 1) * 16384 + (half) * 8192 + (j_ * 512 + w * 64) * 8);\
    }                                                                             \
  }

  f32x4 acc[8][4];
#pragma unroll
  for (int i = 0; i < 8; ++i)
#pragma unroll
    for (int n = 0; n < 4; ++n) acc[i][n] = fz4();

  // bias per lane (epilogue operand), load early
  float bv[4];
#pragma unroll
  for (int nf = 0; nf < 4; ++nf) bv[nf] = bias[n0 + wc + nf * 16 + q];

  // prologue: stage tiles 0 and 1 fully (16 loads/thread)
  STAGE_A(0, 0); STAGE_A(0, 1); STAGE_B(0, 0); STAGE_B(0, 1);
  STAGE_A(1, 0); STAGE_A(1, 1); STAGE_B(1, 0); STAGE_B(1, 1);
  asm volatile("s_waitcnt vmcnt(8)");          // tile 0 landed; tile 1 in flight
  __builtin_amdgcn_s_barrier();

  short8_t bfr[4][2];
  for (int S = 0; S < NT; ++S) {
    const int bs = (S & 1) * 16384;
#pragma unroll
    for (int p = 0; p < 4; ++p) {
      // ---- ds_read register subtiles ----
      short8_t afr[2][2];
#pragma unroll
      for (int mi = 0; mi < 2; ++mi)
#pragma unroll
        for (int kk = 0; kk < 2; ++kk) {
          const int r = (2 * p + mi) * 16 + q;
          afr[mi][kk] = *(const short8_t*)(Al + bs + ah * 8192 + r * 64 +
                                           ((kk * 4 + g) ^ (((r >> 2) & 1) << 1)) * 8);
        }
      if (p == 0) {
#pragma unroll
        for (int nf = 0; nf < 4; ++nf)
#pragma unroll
          for (int kk = 0; kk < 2; ++kk) {
            const int r = brow0 + nf * 16 + q;
            bfr[nf][kk] = *(const short8_t*)(Bl + bs + bh * 8192 + r * 64 +
                                             ((kk * 4 + g) ^ (((r >> 2) & 1) << 1)) * 8);
          }
      }
      // ---- issue one half-tile stage ----
      if (p == 0 && S >= 1 && S + 1 < NT) STAGE_A(S + 1, 0);
      if (p == 1 && S >= 1 && S + 1 < NT) STAGE_A(S + 1, 1);
      if (p == 2 && S + 2 < NT) STAGE_B(S + 2, 0);
      if (p == 3 && S + 2 < NT) STAGE_B(S + 2, 1);
      // ---- counted vmcnt once per K-tile, fencing tile S+1's reads ----
      if (p == 3) {
        if (S == NT - 2) { asm volatile("s_waitcnt vmcnt(0)"); }
        else if (S < NT - 2) { asm volatile("s_waitcnt vmcnt(4)"); }
      }
      __builtin_amdgcn_s_barrier();
      asm volatile("s_waitcnt lgkmcnt(0)" ::: "memory");
      __builtin_amdgcn_sched_barrier(0);
      __builtin_amdgcn_s_setprio(1);
#pragma unroll
      for (int nf = 0; nf < 4; ++nf)
#pragma unroll
        for (int mi = 0; mi < 2; ++mi)
#pragma unroll
          for (int kk = 0; kk < 2; ++kk)
            acc[2 * p + mi][nf] = __builtin_amdgcn_mfma_f32_16x16x32_bf16(
                afr[mi][kk], bfr[nf][kk], acc[2 * p + mi][nf], 0, 0, 0);
      __builtin_amdgcn_s_setprio(0);
      __builtin_amdgcn_s_barrier();
    }
  }
#undef STAGE_A
#undef STAGE_B

  // epilogue: bias + store (C/D: col=lane&15, row=(lane>>4)*4+j)
#pragma unroll
  for (int nf = 0; nf < 4; ++nf) {
    const int col = n0 + wc + nf * 16 + q;
#pragma unroll
    for (int mf = 0; mf < 8; ++mf) {
      const int rowb = m0 + wr + mf * 16 + g * 4;
#pragma unroll
      for (int j = 0; j < 4; ++j) {
        const float vv = acc[mf][nf][j] + bv[nf];
        if (OUT_BF16)
          ((u16*)Cout)[(size_t)(rowb + j) * N + col] = f2bf(vv);
        else
          ((float*)Cout)[(size_t)(rowb + j) * N + col] = vv;
      }
    }
  }
}

// ---------------- V -> V^T per (h,b): VT[hb][d][t] ----------------
__global__ __launch_bounds__(256) void transpose_v(const u16* __restrict__ V,
                                                   u16* __restrict__ VT) {
  __shared__ u16 t[64][68];
  const int hb = blockIdx.z;
  const int t0 = blockIdx.x * 64, d0 = blockIdx.y * 64;
  const u16* src = V + (size_t)hb * 1024 * 256;
  u16* dst = VT + (size_t)hb * 256 * 1024;
  const int tid = threadIdx.x;
#pragma unroll
  for (int i = 0; i < 4; ++i) {
    const int idx = i * 256 + tid;
    const int r = idx >> 4, c4 = (idx & 15) * 4;   // r: t-row, c4: d-col
    ushort4 v = *(const ushort4*)(src + (size_t)(t0 + r) * 256 + d0 + c4);
    *(ushort4*)&t[r][c4] = v;
  }
  __syncthreads();
#pragma unroll
  for (int i = 0; i < 4; ++i) {
    const int idx = i * 256 + tid;
    const int r = idx >> 4, c4 = (idx & 15) * 4;   // r: d-row, c4: t-col
    ushort4 v;
    v.x = t[c4][r]; v.y = t[c4 + 1][r]; v.z = t[c4 + 2][r]; v.w = t[c4 + 3][r];
    *(ushort4*)(dst + (size_t)(d0 + r) * 1024 + t0 + c4) = v;
  }
}

// ---------------- fused attention (swapped-QK, dbuf KT=32, 2-phase pipeline) ----------
// R4 exact configuration (measured 146.7us): 256 threads, 64 q-rows/block.
// Q,K: [hb][1024][256] bf16; VT: [hb][256][1024] bf16; adj: [b][1024][1024] f32
// Block->work mapping: per-XCD order b(outer) -> qb -> h(fastest).
__global__ __launch_bounds__(256, 2) void attn_kernel(const u16* __restrict__ Q,
                                                      const u16* __restrict__ Kf,
                                                      const u16* __restrict__ VT,
                                                      const float* __restrict__ adj,
                                                      u16* __restrict__ O) {
  __shared__ u16 Ks[2][32 * 256];   // dbuf K tile [key][d], 512B rows, XOR slots
  __shared__ u16 Vs[2][256 * 32];   // dbuf V^T tile [d][key], 64B rows, XOR slots
  __shared__ u16 Ps[4][16 * 32];    // per-wave P^T staging, 64B rows, XOR slots
  const int tid = threadIdx.x, w = tid >> 6, l = tid & 63;
  const int g = l >> 4, q = l & 15;
  const int bid = blockIdx.x;
  const int xcd = bid & 7, idx = bid >> 3;           // 8 XCDs x 128 blocks
  const int b = xcd * 2 + (idx >> 6);                // 2 batches per XCD
  const int qb = (idx >> 2) & 15, h = idx & 3;       // qb sweeps, h fastest
  const int hb = h * 16 + b;
  const int q0 = qb * 64;
  const u16* qb_p = Q + ((size_t)hb * 1024 + q0 + w * 16) * 256;
  const u16* kb = Kf + (size_t)hb * 1024 * 256;
  const u16* vtb = VT + (size_t)hb * 256 * 1024;
  const float* adjr = adj + (size_t)b * 1024 * 1024 + (size_t)(q0 + w * 16 + q) * 1024;

  // Q fragments (B-operand of S^T): lane q=l&15, d = kk*32 + g*8 + j
  short8_t qf[8];
#pragma unroll
  for (int kk = 0; kk < 8; ++kk)
    qf[kk] = *(const short8_t*)(qb_p + (size_t)q * 256 + kk * 32 + g * 8);

  f32x4 o[16];  // O^T accum: lane holds O[q][d], d = n*16 + g*4 + r
#pragma unroll
  for (int n = 0; n < 16; ++n) o[n] = fz4();
  float mrun = -1e30f, lrun = 0.f;

#define STAGE_KV(ktt, bufi)                                                        \
  {                                                                                \
    _Pragma("unroll") for (int i_ = 0; i_ < 4; ++i_) {                             \
      const int c_ = w * 4 + i_;                                                   \
      const int row_ = 2 * c_ + (l >> 5);                                          \
      const int gcb_ = ((l & 31) ^ (row_ & 7)) * 16;                               \
      gload_lds16((const char*)(kb + (size_t)((ktt) * 32 + row_) * 256) + gcb_,    \
                  (char*)Ks[bufi] + c_ * 1024);                                    \
    }                                                                              \
    _Pragma("unroll") for (int i_ = 0; i_ < 4; ++i_) {                             \
      const int c_ = w * 4 + i_;                                                   \
      const int dr_ = c_ * 16 + (l >> 2);                                          \
      const int sl_ = (l & 3) ^ ((dr_ >> 1) & 3);                                  \
      gload_lds16((const char*)(vtb + (size_t)dr_ * 1024 + (ktt) * 32) + sl_ * 16, \
                  (char*)Vs[bufi] + c_ * 1024);                                    \
    }                                                                              \
  }

  // prologue: stage tile 0, prefetch adj tile 0
  STAGE_KV(0, 0);
  float4 a0 = *(const float4*)(adjr + 0 * 32 + 0 * 16 + g * 4);
  float4 a1 = *(const float4*)(adjr + 0 * 32 + 1 * 16 + g * 4);
  __syncthreads();

  for (int kt = 0; kt < 32; ++kt) {
    const int cur = kt & 1;
    float4 n0v = a0, n1v = a1;
    if (kt < 31) {
      STAGE_KV(kt + 1, cur ^ 1);
      n0v = *(const float4*)(adjr + (kt + 1) * 32 + 0 * 16 + g * 4);
      n1v = *(const float4*)(adjr + (kt + 1) * 32 + 1 * 16 + g * 4);
    }

    // S^T = K Q^T : 2 key-frags x 8 d-steps. lane: q=l&15, k = f*16 + g*4 + r
    f32x4 s[2];
    const char* kbuf = (const char*)Ks[cur];
    __builtin_amdgcn_s_setprio(1);
#pragma unroll
    for (int f = 0; f < 2; ++f) {
      f32x4 a = fz4();
      const int row = f * 16 + q;
      const char* kr = kbuf + row * 512;
#pragma unroll
      for (int kk = 0; kk < 8; ++kk) {
        const int cb = kk * 64 + g * 16;
        short8_t kfr = *(const short8_t*)(kr + (cb ^ ((row & 7) << 4)));
        a = __builtin_amdgcn_mfma_f32_16x16x32_bf16(kfr, qf[kk], a, 0, 0, 0);
      }
      s[f] = a;
    }
    __builtin_amdgcn_s_setprio(0);

    // scale + adj (vectorized float4 per frag)
#pragma unroll
    for (int j = 0; j < 4; ++j) {
      s[0][j] = s[0][j] * 0.03125f + ((const float*)&a0)[j];
      s[1][j] = s[1][j] * 0.03125f + ((const float*)&a1)[j];
    }

    // per-lane online softmax: 8 local values + reduce across g (xor 16,32)
    float pmax = s[0][0];
#pragma unroll
    for (int j = 1; j < 4; ++j) pmax = fmaxf(pmax, s[0][j]);
#pragma unroll
    for (int j = 0; j < 4; ++j) pmax = fmaxf(pmax, s[1][j]);
    pmax = fmaxf(pmax, __shfl_xor(pmax, 16));
    pmax = fmaxf(pmax, __shfl_xor(pmax, 32));

    if (!__all(pmax - mrun <= 8.0f)) {          // T13 defer-max
      const float mn = fmaxf(mrun, pmax);
      const float al = __expf(mrun - mn);
      mrun = mn;
      lrun *= al;
#pragma unroll
      for (int n = 0; n < 16; ++n)
#pragma unroll
        for (int r = 0; r < 4; ++r) o[n][r] *= al;
    }

    float sum = 0.f;
#pragma unroll
    for (int f = 0; f < 2; ++f)
#pragma unroll
      for (int j = 0; j < 4; ++j) {
        const float p = __expf(s[f][j] - mrun);
        s[f][j] = p;
        sum += p;
      }
    sum += __shfl_xor(sum, 16);
    sum += __shfl_xor(sum, 32);
    lrun += sum;

    // P^T -> LDS (per-wave [q][k] rows of 64B, XOR-swizzled 16B slots)
    {
      char* pw = (char*)Ps[w] + q * 64;
      const int swz = (q >> 1) & 3;
#pragma unroll
      for (int f = 0; f < 2; ++f) {
        ushort4 pk;
        pk.x = f2bf(s[f][0]); pk.y = f2bf(s[f][1]);
        pk.z = f2bf(s[f][2]); pk.w = f2bf(s[f][3]);
        *(ushort4*)(pw + ((f * 32 + g * 8) ^ (swz << 4))) = pk;
      }
    }
    asm volatile("s_waitcnt lgkmcnt(0)");
    __builtin_amdgcn_sched_barrier(0);
    short8_t pa = *(const short8_t*)((const char*)Ps[w] + q * 64 +
                                     ((g * 16) ^ (((q >> 1) & 3) << 4)));

    // O^T += V^T P^T : 16 d-frags, one k-step (K=32 keys)
    const char* vbuf = (const char*)Vs[cur];
    __builtin_amdgcn_s_setprio(1);
#pragma unroll
    for (int n = 0; n < 16; ++n) {
      const int dr = n * 16 + q;
      const int sl = g ^ ((dr >> 1) & 3);
      short8_t vf = *(const short8_t*)(vbuf + dr * 64 + sl * 16);
      o[n] = __builtin_amdgcn_mfma_f32_16x16x32_bf16(vf, pa, o[n], 0, 0, 0);
    }
    __builtin_amdgcn_s_setprio(0);

    __syncthreads();
    a0 = n0v; a1 = n1v;
  }
#undef STAGE_KV

  // epilogue: normalize, packed 8B stores; lane owns row q, d = n*16+g*4+r
  const float inv = 1.0f / lrun;
  u16* ob = O + ((size_t)hb * 1024 + q0 + w * 16 + q) * 256;
#pragma unroll
  for (int n = 0; n < 16; ++n) {
    ushort4 st;
    st.x = f2bf(o[n][0] * inv); st.y = f2bf(o[n][1] * inv);
    st.z = f2bf(o[n][2] * inv); st.w = f2bf(o[n][3] * inv);
    *(ushort4*)(ob + n * 16 + g * 4) = st;
  }
}

extern "C" void kernel_launch(void* const* d_in, const int* in_sizes, int n_in,
                              void* d_out, int out_size, void* d_ws, size_t ws_size,
                              hipStream_t stream) {
  (void)in_sizes; (void)n_in; (void)out_size; (void)ws_size;
  const float* x   = (const float*)d_in[0];
  const float* y   = (const float*)d_in[1];
  const float* adj = (const float*)d_in[2];
  const float* Wq  = (const float*)d_in[3];
  const float* bq  = (const float*)d_in[4];
  const float* Wk  = (const float*)d_in[5];
  const float* bk  = (const float*)d_in[6];
  const float* Wv  = (const float*)d_in[7];
  const float* bv  = (const float*)d_in[8];
  const float* Wo  = (const float*)d_in[9];
  const float* bo  = (const float*)d_in[10];

  char* ws = (char*)d_ws;
  const size_t MB = 1ull << 20;
  u16* Xb  = (u16*)(ws + 0);        // 32MB, reused as Tmp after Q GEMM
  u16* Yb  = (u16*)(ws + 32 * MB);  // 32MB
  u16* Wqb = (u16*)(ws + 64 * MB);  // 2MB each
  u16* Wkb = (u16*)(ws + 66 * MB);
  u16* Wvb = (u16*)(ws + 68 * MB);
  u16* Wob = (u16*)(ws + 70 * MB);
  u16* Qb  = (u16*)(ws + 72 * MB);  // 32MB
  u16* Kb  = (u16*)(ws + 104 * MB);
  u16* Vb  = (u16*)(ws + 136 * MB);
  u16* VTb = (u16*)(ws + 168 * MB); // peak 200MB
  u16* Tmp = Xb;

  cast_kernel<<<16384, 256, 0, stream>>>(x, Xb);
  cast_kernel<<<16384, 256, 0, stream>>>(y, Yb);
  cast_kernel<<<1024, 256, 0, stream>>>(Wq, Wqb);
  cast_kernel<<<1024, 256, 0, stream>>>(Wk, Wkb);
  cast_kernel<<<1024, 256, 0, stream>>>(Wv, Wvb);
  cast_kernel<<<1024, 256, 0, stream>>>(Wo, Wob);

  dim3 gg(4, 64);   // N-tiles x M-tiles (256x256)
  gemm8<1><<<gg, 512, 0, stream>>>(Xb, Wqb, bq, Qb, 16384, 1024, 1024);
  gemm8<1><<<gg, 512, 0, stream>>>(Yb, Wkb, bk, Kb, 16384, 1024, 1024);
  gemm8<1><<<gg, 512, 0, stream>>>(Yb, Wvb, bv, Vb, 16384, 1024, 1024);

  transpose_v<<<dim3(16, 4, 64), 256, 0, stream>>>(Vb, VTb);

  attn_kernel<<<1024, 256, 0, stream>>>(Qb, Kb, VTb, adj, Tmp);

  gemm8<0><<<gg, 512, 0, stream>>>(Tmp, Wob, bo, d_out, 16384, 1024, 1024);
}